// Round 2
// baseline (233.387 us; speedup 1.0000x reference)
//
#include <hip/hip_runtime.h>

// EMA over time: y_t = 0.1*y_{t-1} + 0.9*x_t, x: [B=16, T=4000, C=512] fp32.
// Chunked-scan with truncated warmup: 0.1^8 ~ 1e-8 (well under the 7.8e-3
// tolerance). Each thread owns one (b, c4) column for L=32 timesteps,
// warming up over the previous W=8.
//
// R5: same as R4 (L=32 + nt stores) with the compile fix: hipcc's
// __builtin_nontemporal_store rejects HIP_vector_type float4 — store via a
// native clang ext_vector_type(4) float instead (bit-identical, still one
// global_store_dwordx4 nt).
//
// R4 rationale: the kernel was fabric-bound, not HBM-bound (hbm 1.6-2.5
// TB/s, VALU 3%): L=8/W=8 gave 2.0x read amplification -> 393 MB of
// L2<->MALL traffic at ~4.9 TB/s. Two changes:
//   1. L 8->32: read amplification 2.0x -> 1.25x (-98 MB reads). Main loads
//      split into 2 batches of 16; batch-2 loads are issued into each slot
//      right after it is consumed (peak 24 float4 live, ~115 VGPR, fits the
//      __launch_bounds__(256,4) 128-VGPR cap).
//   2. Nontemporal stores: output is never read; input(131MB)+output(131MB)
//      > 256 MiB L3, so write-allocated output was evicting the resident
//      input. nt stores keep the input L3-resident across launches.

constexpr int B_ = 16;
constexpr int T_ = 4000;
constexpr int C_ = 512;
constexpr int L_ = 32;            // output timesteps per thread
constexpr int W_ = 8;             // lookback warmup (0.1^8 ~ 1e-8)
constexpr int BL_ = 16;           // main-load batch size (2 batches)
constexpr int NC4_ = C_ / 4;      // 128 float4 columns per row
constexpr int NCHUNK_ = T_ / L_;  // 125

typedef float f32x4_ __attribute__((ext_vector_type(4)));

__device__ __forceinline__ void nt_store4(float4* p, const float4& v) {
    f32x4_ t;
    t.x = v.x; t.y = v.y; t.z = v.z; t.w = v.w;
    __builtin_nontemporal_store(t, (f32x4_*)p);
}

__global__ __launch_bounds__(256, 4) void ema_chunk_scan(const float* __restrict__ x,
                                                         float* __restrict__ y) {
    int g = blockIdx.x * blockDim.x + threadIdx.x;
    int c4 = g & (NC4_ - 1);          // lane-major over channels -> coalesced
    int bt = g >> 7;                  // / NC4_
    int b  = bt & (B_ - 1);
    int chunk = bt >> 4;              // / B_  (wave-uniform)

    int t0 = chunk * L_;
    int tw = (chunk > 0) ? (t0 - W_) : 0;

    const float4* base = (const float4*)(x + (size_t)b * T_ * C_) + c4;
    float4*       q    = (float4*)(y + ((size_t)b * T_ + t0) * C_) + c4;

    // ---- issue warmup + batch-1 loads before any use (24 in flight) ----
    float4 w[W_];
    #pragma unroll
    for (int i = 0; i < W_; ++i) w[i] = base[(size_t)(tw + i) * NC4_];
    float4 m[BL_];
    #pragma unroll
    for (int i = 0; i < BL_; ++i) m[i] = base[(size_t)(t0 + i) * NC4_];

    const float a = 0.9f, om = 0.1f;
    float4 acc = make_float4(0.f, 0.f, 0.f, 0.f);

    // Warmup chain (no stores).
    #pragma unroll
    for (int i = 0; i < W_; ++i) {
        acc.x = om * acc.x + a * w[i].x;
        acc.y = om * acc.y + a * w[i].y;
        acc.z = om * acc.z + a * w[i].z;
        acc.w = om * acc.w + a * w[i].w;
    }
    // chunk 0: no history — zero the warmup state (wave-uniform select).
    float sel = (chunk > 0) ? 1.f : 0.f;
    acc.x *= sel; acc.y *= sel; acc.z *= sel; acc.w *= sel;

    // Batch 1: consume slot i, immediately refill it with the batch-2 load
    // (keeps 16 loads in flight continuously; registers reused in place).
    #pragma unroll
    for (int i = 0; i < BL_; ++i) {
        float4 v = m[i];
        m[i] = base[(size_t)(t0 + BL_ + i) * NC4_];
        acc.x = om * acc.x + a * v.x;
        acc.y = om * acc.y + a * v.y;
        acc.z = om * acc.z + a * v.z;
        acc.w = om * acc.w + a * v.w;
        nt_store4(&q[(size_t)i * NC4_], acc);
    }
    // Batch 2.
    #pragma unroll
    for (int i = 0; i < BL_; ++i) {
        acc.x = om * acc.x + a * m[i].x;
        acc.y = om * acc.y + a * m[i].y;
        acc.z = om * acc.z + a * m[i].z;
        acc.w = om * acc.w + a * m[i].w;
        nt_store4(&q[(size_t)(BL_ + i) * NC4_], acc);
    }
}

extern "C" void kernel_launch(void* const* d_in, const int* in_sizes, int n_in,
                              void* d_out, int out_size, void* d_ws, size_t ws_size,
                              hipStream_t stream) {
    const float* x = (const float*)d_in[0];
    float* y = (float*)d_out;
    int total_threads = B_ * NC4_ * NCHUNK_;   // 256,000
    int block = 256;
    int grid = total_threads / block;          // 1000
    ema_chunk_scan<<<grid, block, 0, stream>>>(x, y);
}